// Round 10
// baseline (90.594 us; speedup 1.0000x reference)
//
#include <hip/hip_runtime.h>
#include <math.h>

// SEFusion: x [N=25, C=256, H=48, W=176] f32. V4 = CHW/4 = 540,672 float4.
#define CHW     2162688
#define V4      540672
#define NTOK    25
#define MAXCAV  5
#define NBATCH  8

// reduce geometry: flat 2048 blocks (8/CU exactly), 6600 float4 per block
#define RBLKS   2048
#define CHUNK1  6600             // (NTOK*V4)/RBLKS; spans <= 2 tokens

// apply geometry (R4-proven): 1056 blocks x 512 float4, 2/thread clean
#define ABLKS   1056
#define CHUNK3  512

typedef float f32x4 __attribute__((ext_vector_type(4)));

// ========== Kernel 1: balanced flat reduce, 2 token-buckets per block =====
__global__ __launch_bounds__(256) void k_reduce(const float4* __restrict__ x,
                                                float* __restrict__ ps,
                                                float* __restrict__ pm) {
    const int tid = threadIdx.x;
    const int bid = blockIdx.x;
    const long base  = (long)bid * CHUNK1;
    const int  t0    = (int)(base / V4);
    const int  split = (int)min((long)(t0 + 1) * V4 - base, (long)CHUNK1);

    float s0 = 0.f, s1 = 0.f, m0 = -INFINITY, m1 = -INFINITY;
    // 6600 = 25*256 + 200: 25 full iterations + 1 predicated, fully unrolled
    #pragma unroll
    for (int i = 0; i < 26; ++i) {
        const int li = tid + i * 256;
        if (i < 25 || tid < 200) {
            float4 v = x[base + li];
            const float vs = (v.x + v.y) + (v.z + v.w);
            const float vm = fmaxf(fmaxf(v.x, v.y), fmaxf(v.z, v.w));
            const bool first = li < split;
            s0 += first ? vs : 0.f;
            s1 += first ? 0.f : vs;
            m0 = fmaxf(m0, first ? vm : -INFINITY);
            m1 = fmaxf(m1, first ? -INFINITY : vm);
        }
    }

    const int lane = tid & 63;
    const int wave = tid >> 6;
    #pragma unroll
    for (int off = 32; off > 0; off >>= 1) {
        s0 += __shfl_xor(s0, off, 64);
        s1 += __shfl_xor(s1, off, 64);
        m0 = fmaxf(m0, __shfl_xor(m0, off, 64));
        m1 = fmaxf(m1, __shfl_xor(m1, off, 64));
    }
    __shared__ float rs0[4], rs1[4], rm0[4], rm1[4];
    if (lane == 0) { rs0[wave] = s0; rs1[wave] = s1; rm0[wave] = m0; rm1[wave] = m1; }
    __syncthreads();
    if (tid == 0) {
        ps[2 * bid]     = rs0[0] + rs0[1] + rs0[2] + rs0[3];
        ps[2 * bid + 1] = rs1[0] + rs1[1] + rs1[2] + rs1[3];
        pm[2 * bid]     = fmaxf(fmaxf(rm0[0], rm0[1]), fmaxf(rm0[2], rm0[3]));
        pm[2 * bid + 1] = fmaxf(fmaxf(rm1[0], rm1[1]), fmaxf(rm1[2], rm1[3]));
    }
}

// ========== Kernel 2: gather partials + gate MLP (R6-verified formula) ====
__global__ __launch_bounds__(256) void k_gate(const float* __restrict__ ps,
                                              const float* __restrict__ pm,
                                              const int*   __restrict__ record_len,
                                              const float* __restrict__ W1,
                                              const float* __restrict__ W2,
                                              const float* __restrict__ conv_w,
                                              int*   __restrict__ starts,
                                              float* __restrict__ coefs) {
    __shared__ float tsum[NTOK], tmax[NTOK];
    const int wave = threadIdx.x >> 6;
    const int lane = threadIdx.x & 63;

    for (int t = wave; t < NTOK; t += 4) {
        const int b_lo = (t == 0) ? 0 : ((t - 1) * V4 + CHUNK1 - 1) / CHUNK1;
        const int b_hi = min(RBLKS - 1, ((t + 1) * V4 + CHUNK1 - 1) / CHUNK1 - 1);
        float s = 0.f, m = -INFINITY;
        for (int b = b_lo + lane; b <= b_hi; b += 64) {
            const int tb = (int)(((long)b * CHUNK1) / V4);
            if (tb == t)     { s += ps[2 * b];     m = fmaxf(m, pm[2 * b]); }
            if (tb == t - 1) { s += ps[2 * b + 1]; m = fmaxf(m, pm[2 * b + 1]); }
        }
        #pragma unroll
        for (int off = 32; off > 0; off >>= 1) {
            s += __shfl_xor(s, off, 64);
            m = fmaxf(m, __shfl_xor(m, off, 64));
        }
        if (lane == 0) { tsum[t] = s; tmax[t] = m; }
    }
    __syncthreads();

    if ((int)threadIdx.x < NBATCH) {
        const int b = threadIdx.x;
        int start = 0;
        for (int i = 0; i < b; ++i) start += record_len[i];
        const int len = record_len[b];
        starts[b] = start;

        float xsq[2 * MAXCAV];
        #pragma unroll
        for (int m = 0; m < MAXCAV; ++m) {
            const bool valid = m < len;
            xsq[m]          = valid ? tsum[start + m] * (1.0f / (float)CHW) : 0.0f;
            xsq[MAXCAV + m] = valid ? tmax[start + m] : 0.0f;  // zero-pad: max=0
        }
        float h[MAXCAV];
        #pragma unroll
        for (int j = 0; j < MAXCAV; ++j) {
            float a = 0.0f;
            #pragma unroll
            for (int k = 0; k < 2 * MAXCAV; ++k) a += xsq[k] * W1[j * 2 * MAXCAV + k];
            h[j] = 1.0f / (1.0f + expf(-a));
        }
        #pragma unroll
        for (int m = 0; m < MAXCAV; ++m) {
            float g = 0.0f;
            #pragma unroll
            for (int j = 0; j < MAXCAV; ++j) g += h[j] * W2[m * MAXCAV + j];
            coefs[b * MAXCAV + m] = conv_w[m] * fmaxf(g, 0.0f);
        }
    }
}

// ========== Kernel 3: balanced apply (R4-proven, 512 float4/block) ========
__device__ __forceinline__ void relu_store(float ax, float ay, float az, float aw,
                                           float4* __restrict__ out, int o) {
    f32x4 acc;
    acc.x = fmaxf(ax, 0.0f);
    acc.y = fmaxf(ay, 0.0f);
    acc.z = fmaxf(az, 0.0f);
    acc.w = fmaxf(aw, 0.0f);
    __builtin_nontemporal_store(acc, (f32x4*)(out + o));
}

template <int LEN>
__device__ __forceinline__ void apply_idx(const float4* __restrict__ x,
                                          const float* c, float bias,
                                          int start, int obase, int idx,
                                          float4* __restrict__ out) {
    float ax = bias, ay = bias, az = bias, aw = bias;
    #pragma unroll
    for (int m = 0; m < LEN; ++m) {
        float4 v = x[(start + m) * V4 + idx];
        ax += c[m] * v.x;
        ay += c[m] * v.y;
        az += c[m] * v.z;
        aw += c[m] * v.w;
    }
    relu_store(ax, ay, az, aw, out, obase + idx);
}

template <int LEN>
__device__ __forceinline__ void apply_pair(const float4* __restrict__ x,
                                           const float* c, float bias,
                                           int start, int obase, int idx0,
                                           float4* __restrict__ out) {
    apply_idx<LEN>(x, c, bias, start, obase, idx0, out);
    apply_idx<LEN>(x, c, bias, start, obase, idx0 + 256, out);
}

__global__ __launch_bounds__(256) void k_apply(const float4* __restrict__ x,
                                               const int*   __restrict__ record_len,
                                               const int*   __restrict__ starts,
                                               const float* __restrict__ coefs,
                                               const float* __restrict__ conv_b,
                                               float4* __restrict__ out) {
    const int tid  = threadIdx.x;
    const int idx0 = blockIdx.x * CHUNK3 + tid;
    const float bias = conv_b[0];

    for (int b = 0; b < NBATCH; ++b) {
        const int len   = record_len[b];
        const int start = starts[b];
        float c[MAXCAV];
        #pragma unroll
        for (int m = 0; m < MAXCAV; ++m) c[m] = coefs[b * MAXCAV + m];
        const int obase = b * V4;

        switch (len) {
            case 1:  apply_pair<1>(x, c, bias, start, obase, idx0, out); break;
            case 2:  apply_pair<2>(x, c, bias, start, obase, idx0, out); break;
            case 3:  apply_pair<3>(x, c, bias, start, obase, idx0, out); break;
            case 4:  apply_pair<4>(x, c, bias, start, obase, idx0, out); break;
            default: apply_pair<5>(x, c, bias, start, obase, idx0, out); break;
        }
    }
}

extern "C" void kernel_launch(void* const* d_in, const int* in_sizes, int n_in,
                              void* d_out, int out_size, void* d_ws, size_t ws_size,
                              hipStream_t stream) {
    const float4* x  = (const float4*)d_in[0];
    const int*    rl = (const int*)d_in[1];
    const float*  W1 = (const float*)d_in[2];
    const float*  W2 = (const float*)d_in[3];
    const float*  cw = (const float*)d_in[4];
    const float*  cb = (const float*)d_in[5];
    float4* out = (float4*)d_out;

    char* ws = (char*)d_ws;
    float* ps     = (float*)(ws);                  // 2*RBLKS floats = 16 KB
    float* pm     = (float*)(ws + 16384);          // 16 KB
    int*   starts = (int*)  (ws + 32768);          // 8 ints (+pad)
    float* coefs  = (float*)(ws + 32768 + 64);     // 40 floats

    k_reduce<<<RBLKS, 256, 0, stream>>>(x, ps, pm);
    k_gate<<<1, 256, 0, stream>>>(ps, pm, rl, W1, W2, cw, starts, coefs);
    k_apply<<<ABLKS, 256, 0, stream>>>(x, rl, starts, coefs, cb, out);
}

// Round 11
// 81.976 us; speedup vs baseline: 1.1051x; 1.1051x over previous
//
#include <hip/hip_runtime.h>
#include <math.h>

// SEFusion: x [N=25, C=256, H=48, W=176] f32. V4 = CHW/4 = 540,672 float4.
#define CHW     2162688
#define V4      540672
#define NTOK    25
#define MAXCAV  5
#define NBATCH  8

// reduce geometry (R4-proven): per-token segments, compile-time trip count
#define BPT     64               // blocks per token
#define V4_BLK  8448             // V4 / BPT
#define ITERS   33               // V4_BLK / 256

// apply geometry (R4-proven): 1056 blocks x 512 float4, 2/thread clean
#define ABLKS   1056
#define CHUNK3  512

typedef float f32x4 __attribute__((ext_vector_type(4)));

// =================== Kernel 1: per-token sum + max (R4) ====================
__global__ __launch_bounds__(256) void k_reduce(const float4* __restrict__ x,
                                                float* __restrict__ psum,
                                                float* __restrict__ pmax) {
    const int tid = threadIdx.x;
    const int t   = blockIdx.y;      // token
    const int blk = blockIdx.x;      // 0..BPT-1
    const long base = (long)t * V4 + (long)blk * V4_BLK;

    float s = 0.0f;
    float mx = -INFINITY;
    #pragma unroll 4
    for (int i = 0; i < ITERS; ++i) {
        float4 v = x[base + i * 256 + tid];
        s += (v.x + v.y) + (v.z + v.w);
        mx = fmaxf(mx, fmaxf(fmaxf(v.x, v.y), fmaxf(v.z, v.w)));
    }

    const int lane = tid & 63;
    const int wave = tid >> 6;
    #pragma unroll
    for (int off = 32; off > 0; off >>= 1) {
        s += __shfl_xor(s, off, 64);
        mx = fmaxf(mx, __shfl_xor(mx, off, 64));
    }
    __shared__ float rs[4], rm[4];
    if (lane == 0) { rs[wave] = s; rm[wave] = mx; }
    __syncthreads();
    if (tid == 0) {
        psum[t * BPT + blk] = rs[0] + rs[1] + rs[2] + rs[3];
        pmax[t * BPT + blk] = fmaxf(fmaxf(rm[0], rm[1]), fmaxf(rm[2], rm[3]));
    }
}

// ========= Kernel 2: finish reduction + gate MLP + per-token tables ========
__global__ __launch_bounds__(256) void k_gate(const float* __restrict__ psum,
                                              const float* __restrict__ pmax,
                                              const int*   __restrict__ record_len,
                                              const float* __restrict__ W1,
                                              const float* __restrict__ W2,
                                              const float* __restrict__ conv_w,
                                              float* __restrict__ tok_coef,  // [NTOK]
                                              int*   __restrict__ tok_end)   // [NTOK]
{
    __shared__ float tsum[NTOK], tmax[NTOK];
    __shared__ float scoef[NBATCH][MAXCAV];
    __shared__ int   sstart[NBATCH], slen[NBATCH];
    const int wave = threadIdx.x >> 6;
    const int lane = threadIdx.x & 63;
    const int tid  = threadIdx.x;

    for (int t = wave; t < NTOK; t += 4) {
        float s = psum[t * BPT + lane];
        float m = pmax[t * BPT + lane];
        #pragma unroll
        for (int off = 32; off > 0; off >>= 1) {
            s += __shfl_xor(s, off, 64);
            m = fmaxf(m, __shfl_xor(m, off, 64));
        }
        if (lane == 0) { tsum[t] = s; tmax[t] = m; }
    }
    __syncthreads();

    if (tid < NBATCH) {
        const int b = tid;
        int start = 0;
        for (int i = 0; i < b; ++i) start += record_len[i];
        const int len = record_len[b];
        sstart[b] = start;
        slen[b]   = len;

        float xsq[2 * MAXCAV];
        #pragma unroll
        for (int m = 0; m < MAXCAV; ++m) {
            const bool valid = m < len;
            xsq[m]          = valid ? tsum[start + m] * (1.0f / (float)CHW) : 0.0f;
            xsq[MAXCAV + m] = valid ? tmax[start + m] : 0.0f;  // zero-pad: max=0
        }
        float h[MAXCAV];
        #pragma unroll
        for (int j = 0; j < MAXCAV; ++j) {
            float a = 0.0f;
            #pragma unroll
            for (int k = 0; k < 2 * MAXCAV; ++k) a += xsq[k] * W1[j * 2 * MAXCAV + k];
            h[j] = 1.0f / (1.0f + expf(-a));
        }
        #pragma unroll
        for (int m = 0; m < MAXCAV; ++m) {
            float g = 0.0f;
            #pragma unroll
            for (int j = 0; j < MAXCAV; ++j) g += h[j] * W2[m * MAXCAV + j];
            scoef[b][m] = conv_w[m] * fmaxf(g, 0.0f);
        }
    }
    __syncthreads();

    // per-token table: coef for token t, and whether t closes its batch
    if (tid < NTOK) {
        int b = 0;
        #pragma unroll
        for (int i = 0; i < NBATCH; ++i)
            if (tid >= sstart[i] + slen[i]) b = i + 1;
        const int m = tid - sstart[b];
        tok_coef[tid] = scoef[b][m];
        tok_end[tid]  = (m == slen[b] - 1) ? b : -1;
    }
}

// ===== Kernel 3: flat 25-token apply — 50 independent loads per thread =====
__device__ __forceinline__ void relu_store(f32x4 a, float4* __restrict__ out, int o) {
    f32x4 acc;
    acc.x = fmaxf(a.x, 0.0f);
    acc.y = fmaxf(a.y, 0.0f);
    acc.z = fmaxf(a.z, 0.0f);
    acc.w = fmaxf(a.w, 0.0f);
    __builtin_nontemporal_store(acc, (f32x4*)(out + o));
}

__global__ __launch_bounds__(256) void k_apply(const float4* __restrict__ x,
                                               const float* __restrict__ tok_coef,
                                               const int*   __restrict__ tok_end,
                                               const float* __restrict__ conv_b,
                                               float4* __restrict__ out) {
    const int tid = threadIdx.x;
    const int idx = blockIdx.x * CHUNK3 + tid;      // and idx+256
    const float bias = conv_b[0];

    // uniform table -> scalar registers
    float tc[NTOK];
    int   te[NTOK];
    #pragma unroll
    for (int t = 0; t < NTOK; ++t) { tc[t] = tok_coef[t]; te[t] = tok_end[t]; }

    f32x4 a0, a1;
    a0.x = a0.y = a0.z = a0.w = bias;
    a1 = a0;

    #pragma unroll
    for (int t = 0; t < NTOK; ++t) {
        const float4 v0 = x[t * V4 + idx];
        const float4 v1 = x[t * V4 + idx + 256];
        const float c = tc[t];
        a0.x += c * v0.x;  a0.y += c * v0.y;  a0.z += c * v0.z;  a0.w += c * v0.w;
        a1.x += c * v1.x;  a1.y += c * v1.y;  a1.z += c * v1.z;  a1.w += c * v1.w;
        if (te[t] >= 0) {                     // uniform branch: store + reset
            const int obase = te[t] * V4 + idx;
            relu_store(a0, out, obase);
            relu_store(a1, out, obase + 256);
            a0.x = a0.y = a0.z = a0.w = bias;
            a1 = a0;
        }
    }
}

extern "C" void kernel_launch(void* const* d_in, const int* in_sizes, int n_in,
                              void* d_out, int out_size, void* d_ws, size_t ws_size,
                              hipStream_t stream) {
    const float4* x  = (const float4*)d_in[0];
    const int*    rl = (const int*)d_in[1];
    const float*  W1 = (const float*)d_in[2];
    const float*  W2 = (const float*)d_in[3];
    const float*  cw = (const float*)d_in[4];
    const float*  cb = (const float*)d_in[5];
    float4* out = (float4*)d_out;

    char* ws = (char*)d_ws;
    float* psum     = (float*)(ws);                // 1600 floats
    float* pmax     = (float*)(ws + 6400);         // 1600 floats
    float* tok_coef = (float*)(ws + 12800);        // 25 floats
    int*   tok_end  = (int*)  (ws + 12800 + 128);  // 25 ints

    k_reduce<<<dim3(BPT, NTOK), 256, 0, stream>>>(x, psum, pmax);
    k_gate<<<1, 256, 0, stream>>>(psum, pmax, rl, W1, W2, cw, tok_coef, tok_end);
    k_apply<<<ABLKS, 256, 0, stream>>>(x, tok_coef, tok_end, cb, out);
}